// Round 4
// baseline (740.210 us; speedup 1.0000x reference)
//
#include <hip/hip_runtime.h>

#define BB 8
#define CC 64
#define OO 128
#define NN 4096
#define KNN 20
#define NT 256          // 16-j tiles per batch scan
#define NCH 4           // merge chunks = per-row col-classes (g)
#define RING 9          // per-lane LDS ring slots (72B stride: no bank alias!)
#define TRIG 5          // drain when any lane cnt>=5 (growth <=4/tile -> <=8)
#define SPLITW 192      // xsp row: 64 bf16 h | 64 bf16 m | 64 bf16 l (384 B)
#define TILEB (16 * SPLITW * 2)  // 6144 B per 16-row B tile

typedef short bf16x8 __attribute__((ext_vector_type(8)));
typedef float f32x4 __attribute__((ext_vector_type(4)));
typedef const __attribute__((address_space(1))) unsigned int* gas_ptr;
typedef __attribute__((address_space(3))) unsigned int* las_ptr;

// ===========================================================================
// Top-20: UNSORTED slots + cached (kmax,kpos); kpos eviction + argmax tree.
// Proven R5-R16. NAMED SCALARS only (R2: no SROA).
// Ledger: R18/R19 occupancy knobs -> no effect (pinned ~22%). R20 intra-
// region reorder -> no effect (compiler already optimal in-region). Barrier
// count 65->128 -> -10% (R18). => The wall is the barrier-lockstep itself.
// R21: ZERO barriers. Wave-private staging: each wave stages its own full
// tile stream (6 x global_load_lds/tile) into a private 2-tile dbuf,
// depth-2 prefetch, counted "s_waitcnt vmcnt(6)" (T4 discipline; vmcnt(0)
// only for the final tile). B-frag reads are inline-asm ds_read_b128 (so
// the compiler waitcnt pass cannot insert a conservative drain), then
// lgkmcnt(0) + sched_barrier(0) (rule 18). Waves free-run; cross-wave
// sharing is gone (4x L2 staging reads, ~13 TB/s < 34.5 TB/s ceiling).
// ===========================================================================
#define REP20(F, P) F(P,0) F(P,1) F(P,2) F(P,3) F(P,4) F(P,5) F(P,6) F(P,7) \
    F(P,8) F(P,9) F(P,10) F(P,11) F(P,12) F(P,13) F(P,14) F(P,15) F(P,16)   \
    F(P,17) F(P,18) F(P,19)

#define TS_DECL(P,k) float P##m##k = 1e30f; int P##p##k = -1;
#define TS_REPL(P,k)                                                        \
  { const bool _h = (P##kpos == (k));                                       \
    P##m##k = _h ? _d : P##m##k;                                            \
    P##p##k = _h ? _j : P##p##k; }

#define TS_N(vd, xd, va, xa, vb, xb)                                        \
  { const bool _g = (vb) > (va); vd = _g ? (vb) : (va); xd = _g ? (xb) : (xa); }

#define TS_TREE(P)                                                          \
  { float t0,t1,t2,t3,t4,t5,t6,t7,t8,t9; int y0,y1,y2,y3,y4,y5,y6,y7,y8,y9; \
    TS_N(t0,y0, P##m0,0,  P##m1,1)   TS_N(t1,y1, P##m2,2,  P##m3,3)         \
    TS_N(t2,y2, P##m4,4,  P##m5,5)   TS_N(t3,y3, P##m6,6,  P##m7,7)         \
    TS_N(t4,y4, P##m8,8,  P##m9,9)   TS_N(t5,y5, P##m10,10, P##m11,11)      \
    TS_N(t6,y6, P##m12,12, P##m13,13) TS_N(t7,y7, P##m14,14, P##m15,15)     \
    TS_N(t8,y8, P##m16,16, P##m17,17) TS_N(t9,y9, P##m18,18, P##m19,19)     \
    float u0,u1,u2,u3,u4; int z0,z1,z2,z3,z4;                               \
    TS_N(u0,z0, t0,y0, t1,y1) TS_N(u1,z1, t2,y2, t3,y3)                     \
    TS_N(u2,z2, t4,y4, t5,y5) TS_N(u3,z3, t6,y6, t7,y7)                     \
    TS_N(u4,z4, t8,y8, t9,y9)                                               \
    float w0,w1; int q0,q1;                                                 \
    TS_N(w0,q0, u0,z0, u1,z1) TS_N(w1,q1, u2,z2, u3,z3)                     \
    float e0; int r0;                                                       \
    TS_N(e0,r0, w0,q0, w1,q1)                                               \
    TS_N(P##kmax, P##kpos, e0,r0, u4,z4) }

#define TS_INS(P, dval, jval)                                               \
  { const float _d = (dval); const int _j = (jval);                         \
    REP20(TS_REPL, P)                                                       \
    TS_TREE(P) }

// row-threshold refresh: rt = min(kmax over the 4 lanes sharing myrow)
#define RT_UPDATE                                                           \
  { const int _s1 = __builtin_amdgcn_ds_swizzle(__float_as_int(A_kmax), 0x101F); \
    const float _m1 = fminf(A_kmax, __int_as_float(_s1));                   \
    const int _s2 = __builtin_amdgcn_ds_swizzle(__float_as_int(_m1), 0x201F); \
    rt = fminf(_m1, __int_as_float(_s2)); }

__device__ __forceinline__ unsigned rne_bf16(float f) {
  const unsigned u = __float_as_uint(f);
  return (u + 0x7fffu + ((u >> 16) & 1u)) >> 16;
}

// ---------------------------------------------------------------------------
// Kernel 1: per-point precompute (unchanged from R14).
// ---------------------------------------------------------------------------
__global__ __launch_bounds__(128, 3) void precompute_kernel(
    const float* __restrict__ x, const float* __restrict__ W,
    const float* __restrict__ bias, unsigned short* __restrict__ Ab16,
    float* __restrict__ Q, float* __restrict__ xsq,
    unsigned short* __restrict__ xsp) {
  const int b = blockIdx.y;
  const int n = blockIdx.x * 128 + threadIdx.x;
  const float* xb = x + (size_t)b * CC * NN;

  float xr[CC];
  float sq = 0.f;
#pragma unroll
  for (int c = 0; c < CC; ++c) {
    xr[c] = xb[(size_t)c * NN + n];
    sq = fmaf(xr[c], xr[c], sq);
  }
  xsq[(size_t)b * NN + n] = sq;

  unsigned* srow = (unsigned*)(xsp + ((size_t)b * NN + n) * SPLITW);
#pragma unroll
  for (int c = 0; c < CC; c += 2) {
    const unsigned h0 = rne_bf16(xr[c]), h1 = rne_bf16(xr[c + 1]);
    const float r0 = xr[c] - __uint_as_float(h0 << 16);
    const float r1 = xr[c + 1] - __uint_as_float(h1 << 16);
    const unsigned m0 = rne_bf16(r0), m1 = rne_bf16(r1);
    const float s0 = r0 - __uint_as_float(m0 << 16);
    const float s1 = r1 - __uint_as_float(m1 << 16);
    const unsigned l0 = rne_bf16(s0), l1 = rne_bf16(s1);
    srow[c / 2] = h0 | (h1 << 16);
    srow[32 + c / 2] = m0 | (m1 << 16);
    srow[64 + c / 2] = l0 | (l1 << 16);
  }

  unsigned short* Arow = Ab16 + ((size_t)b * NN + n) * OO;
  float* Qrow = Q + ((size_t)b * NN + n) * OO;

  for (int og = 0; og < OO; og += 4) {
    float p[4] = {0.f, 0.f, 0.f, 0.f};
    float g[4] = {0.f, 0.f, 0.f, 0.f};
#pragma unroll
    for (int oo = 0; oo < 4; ++oo) {
      const float* wr = W + (size_t)(og + oo) * (2 * CC);
#pragma unroll
      for (int c = 0; c < CC; c += 4) {
        float4 w1 = *(const float4*)(wr + c);
        float4 w2 = *(const float4*)(wr + CC + c);
        p[oo] = fmaf(w1.x, xr[c], p[oo]);
        p[oo] = fmaf(w1.y, xr[c + 1], p[oo]);
        p[oo] = fmaf(w1.z, xr[c + 2], p[oo]);
        p[oo] = fmaf(w1.w, xr[c + 3], p[oo]);
        g[oo] = fmaf(w2.x, xr[c], g[oo]);
        g[oo] = fmaf(w2.y, xr[c + 1], g[oo]);
        g[oo] = fmaf(w2.z, xr[c + 2], g[oo]);
        g[oo] = fmaf(w2.w, xr[c + 3], g[oo]);
      }
    }
    const unsigned pa0 = rne_bf16(p[0]) | (rne_bf16(p[1]) << 16);
    const unsigned pa1 = rne_bf16(p[2]) | (rne_bf16(p[3]) << 16);
    *(uint2*)(Arow + og) = make_uint2(pa0, pa1);
    float4 qv = make_float4(g[0] - p[0] + bias[og + 0], g[1] - p[1] + bias[og + 1],
                            g[2] - p[2] + bias[og + 2], g[3] - p[3] + bias[og + 3]);
    *(float4*)(Qrow + og) = qv;
  }
}

// ---------------------------------------------------------------------------
// Kernel 2: MFMA Gram-matrix kNN, wave-private staging, ZERO barriers.
// Each wave stages its own tile stream: 6 x global_load_lds (16B/lane) per
// tile into a private 2-tile double buffer. Swizzle (proven R16): LDS slot
// k*1024 + lane*16 <- global tb + c*384 + q*16 + k*64; fragment reads at
// base + c*16 + q*256 with immediate offsets k*1024.
// ---------------------------------------------------------------------------
#define WAITV(N)                                                            \
  asm volatile("s_waitcnt vmcnt(" #N ")" ::: "memory");                     \
  __builtin_amdgcn_sched_barrier(0);

#define LGKM0                                                               \
  asm volatile("s_waitcnt lgkmcnt(0)" ::: "memory");                        \
  __builtin_amdgcn_sched_barrier(0);

#define STAGEW(T, PB)                                                       \
  { const char* tb = (const char*)xspB + (size_t)(T) * TILEB + gof;         \
    char* lb = (char*)(PB);                                                 \
    __builtin_amdgcn_global_load_lds((gas_ptr)(const void*)(tb), (las_ptr)(void*)(lb), 16, 0, 0); \
    __builtin_amdgcn_global_load_lds((gas_ptr)(const void*)(tb + 64), (las_ptr)(void*)(lb + 1024), 16, 0, 0); \
    __builtin_amdgcn_global_load_lds((gas_ptr)(const void*)(tb + 128), (las_ptr)(void*)(lb + 2048), 16, 0, 0); \
    __builtin_amdgcn_global_load_lds((gas_ptr)(const void*)(tb + 192), (las_ptr)(void*)(lb + 3072), 16, 0, 0); \
    __builtin_amdgcn_global_load_lds((gas_ptr)(const void*)(tb + 256), (las_ptr)(void*)(lb + 4096), 16, 0, 0); \
    __builtin_amdgcn_global_load_lds((gas_ptr)(const void*)(tb + 320), (las_ptr)(void*)(lb + 5120), 16, 0, 0); }

// 6 B-fragments via inline-asm ds_read_b128 (invisible to compiler waitcnt
// pass -> our counted vmcnt is the only guard; early-clobber outputs).
#define READB6(RA)                                                          \
  bf16x8 Bh0, Bh1, Bm0, Bm1, Bl0, Bl1;                                      \
  asm volatile("ds_read_b128 %0, %6 offset:0\n\t"                           \
               "ds_read_b128 %1, %6 offset:1024\n\t"                        \
               "ds_read_b128 %2, %6 offset:2048\n\t"                        \
               "ds_read_b128 %3, %6 offset:3072\n\t"                        \
               "ds_read_b128 %4, %6 offset:4096\n\t"                        \
               "ds_read_b128 %5, %6 offset:5120"                            \
               : "=&v"(Bh0), "=&v"(Bh1), "=&v"(Bm0), "=&v"(Bm1),            \
                 "=&v"(Bl0), "=&v"(Bl1)                                     \
               : "v"(RA));

#define TILE_MFMA_BODY(WBUF)                                                \
    f32x4 ac0 = {0.f, 0.f, 0.f, 0.f};                                       \
    f32x4 ac1 = {0.f, 0.f, 0.f, 0.f};                                       \
    f32x4 ac2 = {0.f, 0.f, 0.f, 0.f};                                       \
    f32x4 ac3 = {0.f, 0.f, 0.f, 0.f};                                       \
    ac0 = __builtin_amdgcn_mfma_f32_16x16x32_bf16(Ah0, Bh0, ac0, 0, 0, 0);  \
    ac1 = __builtin_amdgcn_mfma_f32_16x16x32_bf16(Ah1, Bh1, ac1, 0, 0, 0);  \
    ac2 = __builtin_amdgcn_mfma_f32_16x16x32_bf16(Ah0, Bm0, ac2, 0, 0, 0);  \
    ac3 = __builtin_amdgcn_mfma_f32_16x16x32_bf16(Ah1, Bm1, ac3, 0, 0, 0);  \
    ac0 = __builtin_amdgcn_mfma_f32_16x16x32_bf16(Am0, Bh0, ac0, 0, 0, 0);  \
    ac1 = __builtin_amdgcn_mfma_f32_16x16x32_bf16(Am1, Bh1, ac1, 0, 0, 0);  \
    ac2 = __builtin_amdgcn_mfma_f32_16x16x32_bf16(Ah0, Bl0, ac2, 0, 0, 0);  \
    ac3 = __builtin_amdgcn_mfma_f32_16x16x32_bf16(Ah1, Bl1, ac3, 0, 0, 0);  \
    ac0 = __builtin_amdgcn_mfma_f32_16x16x32_bf16(Al0, Bh0, ac0, 0, 0, 0);  \
    ac1 = __builtin_amdgcn_mfma_f32_16x16x32_bf16(Al1, Bh1, ac1, 0, 0, 0);  \
    ac2 = __builtin_amdgcn_mfma_f32_16x16x32_bf16(Am0, Bm0, ac2, 0, 0, 0);  \
    ac3 = __builtin_amdgcn_mfma_f32_16x16x32_bf16(Am1, Bm1, ac3, 0, 0, 0);  \
    const f32x4 acc = (ac0 + ac1) + (ac2 + ac3);                            \
    float* bw = &bounce[WBUF][wv][0];                                       \
    bw[(q * 4 + 0) * 20 + c] = acc[0];                                      \
    bw[(q * 4 + 1) * 20 + c] = acc[1];                                      \
    bw[(q * 4 + 2) * 20 + c] = acc[2];                                      \
    bw[(q * 4 + 3) * 20 + c] = acc[3];

#define TILE_VALS(T, SB)                                                    \
  const float* br = &bounce[SB][wv][myrow * 20 + 4 * g];                    \
  const f32x4 dots = *(const f32x4*)br;                                     \
  const float4 xx = *(const float4*)(xsqb + (T) * 16 + 4 * g);              \
  const float d0 = fmaf(-2.f, dots[0], xx.x);                               \
  const float d1 = fmaf(-2.f, dots[1], xx.y);                               \
  const float d2 = fmaf(-2.f, dots[2], xx.z);                               \
  const float d3 = fmaf(-2.f, dots[3], xx.w);                               \
  const int jb = (T) * 16 + 4 * g;

#define POST_SELF(K0, K1, K2, K3)                                           \
    A_m##K0 = d0; A_p##K0 = jb;                                             \
    A_m##K1 = d1; A_p##K1 = jb + 1;                                         \
    A_m##K2 = d2; A_p##K2 = jb + 2;                                         \
    A_m##K3 = d3; A_p##K3 = jb + 3;

// RT_UPDATE only inside the drain: kmax (hence rt) can only change when
// TS_INS runs; drain branch is wave-uniform (ballot) so swizzle is safe.
#define POST_SEL                                                            \
    if (d0 <= rt) { myring[cnt] = make_float2(d0, __int_as_float(jb)); ++cnt; } \
    if (d1 <= rt) { myring[cnt] = make_float2(d1, __int_as_float(jb + 1)); ++cnt; } \
    if (d2 <= rt) { myring[cnt] = make_float2(d2, __int_as_float(jb + 2)); ++cnt; } \
    if (d3 <= rt) { myring[cnt] = make_float2(d3, __int_as_float(jb + 3)); ++cnt; } \
    if (__ballot(cnt >= TRIG)) {                                            \
      for (int _k = 0; _k < cnt; ++_k) {                                    \
        const float2 e = myring[_k];                                        \
        if (e.x < A_kmax) { TS_INS(A_, e.x, __float_as_int(e.y)) }          \
      }                                                                     \
      cnt = 0;                                                              \
      RT_UPDATE                                                             \
    }

// One pipeline step: wait tile T's staging (counted), read frags, MFMA,
// select tile T-1 (POST consumes d0..d3/jb), then stage T+2 (pinned last).
#define ITER(RA, WB, SB, TSEL, POST, TNEXT, PB)                             \
  { WAITV(6)                                                                \
    READB6(RA)                                                              \
    LGKM0                                                                   \
    TILE_MFMA_BODY(WB)                                                      \
    { TILE_VALS(TSEL, SB) POST }                                            \
    __builtin_amdgcn_sched_barrier(0);                                      \
    STAGEW(TNEXT, PB) }

__global__ __launch_bounds__(256, 2) void knn_kernel(
    const unsigned short* __restrict__ xsp, const float* __restrict__ xsq,
    float* __restrict__ cd, int* __restrict__ ci) {
  __shared__ unsigned short Bbuf[4][2][TILEB / 2];  // 48 KB: per-wave dbuf
  __shared__ float bounce[2][4][16 * 20];           // 10 KB
  __shared__ float2 ring[256][RING];                // 18 KB  => 76.5 KB

  const int b = blockIdx.y;
  const int wv = threadIdx.x >> 6;
  const int lane = threadIdx.x & 63;
  const int q = lane >> 4;
  const int c = lane & 15;
  const int c16 = c * 16;
  const int gof = c * 384 + q * 16;  // staging source offset (k adds 64)
  const int ibase = blockIdx.x * 64 + wv * 16;
  const int myrow = q * 4 + (c & 3);
  const int g = c >> 2;
  const int isel = ibase + myrow;

  const unsigned short* xspB = xsp + (size_t)b * NN * SPLITW;
  const float* xsqb = xsq + (size_t)b * NN;

  char* pb0 = (char*)&Bbuf[wv][0][0];
  char* pb1 = (char*)&Bbuf[wv][1][0];
  const las_ptr ra0 = (las_ptr)(void*)(pb0 + c16 + q * 256);
  const las_ptr ra1 = (las_ptr)(void*)(pb1 + c16 + q * 256);

  // A fragments: rows ibase+c, k-slice quad*8 (+32 for k-chunk 1)
  const unsigned short* arow = xspB + (size_t)(ibase + c) * SPLITW + q * 8;
  const bf16x8 Ah0 = *(const bf16x8*)(arow);
  const bf16x8 Ah1 = *(const bf16x8*)(arow + 32);
  const bf16x8 Am0 = *(const bf16x8*)(arow + 64);
  const bf16x8 Am1 = *(const bf16x8*)(arow + 96);
  const bf16x8 Al0 = *(const bf16x8*)(arow + 128);
  const bf16x8 Al1 = *(const bf16x8*)(arow + 160);

  REP20(TS_DECL, A_)
  float A_kmax = 1e30f; int A_kpos = 0;
  float rt = 1e30f;
  float2* myring = ring[threadIdx.x];
  int cnt = 0;

  // ---- prologue: prime depth-2 pipeline ----
  STAGEW(0, pb0)
  STAGEW(1, pb1)

  // t=0: compute tile 0 (no selection yet)
  { WAITV(6) READB6(ra0) LGKM0 TILE_MFMA_BODY(0)
    __builtin_amdgcn_sched_barrier(0); STAGEW(2, pb0) }
  // t=1..4: compute 1..4, bootstrap-fill slots from tiles 0..3
  ITER(ra1, 1, 0, 0, POST_SELF(0, 1, 2, 3), 3, pb1)
  ITER(ra0, 0, 1, 1, POST_SELF(4, 5, 6, 7), 4, pb0)
  ITER(ra1, 1, 0, 2, POST_SELF(8, 9, 10, 11), 5, pb1)
  ITER(ra0, 0, 1, 3, POST_SELF(12, 13, 14, 15), 6, pb0)
  // t=5: compute 5, fill slots 16..19 from tile 4, then tree + rt
  { WAITV(6) READB6(ra1) LGKM0 TILE_MFMA_BODY(1)
    { TILE_VALS(4, 0) POST_SELF(16, 17, 18, 19) }
    TS_TREE(A_)
    RT_UPDATE
    __builtin_amdgcn_sched_barrier(0); STAGEW(7, pb1) }

  // ---- steady state: t = 6..253 (pairs), select t-1/t, stage t+2/t+3 ----
  for (int t = 6; t < 254; t += 2) {
    ITER(ra0, 0, 1, t - 1, POST_SEL, t + 2, pb0)
    ITER(ra1, 1, 0, t, POST_SEL, t + 3, pb1)
  }

  // ---- epilogue: tiles 254, 255 (no staging), final selections ----
  { WAITV(6) READB6(ra0) LGKM0 TILE_MFMA_BODY(0)
    { TILE_VALS(253, 1) POST_SEL } }
  { WAITV(0) READB6(ra1) LGKM0 TILE_MFMA_BODY(1)
    { TILE_VALS(254, 0) POST_SEL } }
  { TILE_VALS(255, 1) POST_SEL }

  // final drain
  for (int _k = 0; _k < cnt; ++_k) {
    const float2 e = myring[_k];
    if (e.x < A_kmax) { TS_INS(A_, e.x, __float_as_int(e.y)) }
  }

  const size_t base = ((size_t)(b * NCH + g) * KNN) * NN + isel;
#define TS_ST(P,k) cd[base + (size_t)(k) * NN] = P##m##k; \
                   ci[base + (size_t)(k) * NN] = P##p##k;
  REP20(TS_ST, A_)
#undef TS_ST
}

// ---------------------------------------------------------------------------
// Kernel 3: merge NCH=4 unsorted 20-lists (lex (d, j) compare — exact jax).
// ---------------------------------------------------------------------------
#define TK_LIST(OP) OP(0) OP(1) OP(2) OP(3) OP(4) OP(5) OP(6) OP(7) OP(8) \
    OP(9) OP(10) OP(11) OP(12) OP(13) OP(14) OP(15) OP(16) OP(17) OP(18) OP(19)
#define TK_DECL(k) float td##k = 1e30f; int ti##k = -1;
#define TK_SW(a, b)                                                        \
  {                                                                        \
    const bool _s = (td##b < td##a) ||                                     \
                    ((td##b == td##a) && (ti##b < ti##a));                 \
    const float _fa = _s ? td##b : td##a;                                  \
    const float _fb = _s ? td##a : td##b;                                  \
    const int _ia = _s ? ti##b : ti##a;                                    \
    const int _ib = _s ? ti##a : ti##b;                                    \
    td##a = _fa; td##b = _fb; ti##a = _ia; ti##b = _ib;                    \
  }
#define TK_BUBBLE                                                          \
  TK_SW(18, 19) TK_SW(17, 18) TK_SW(16, 17) TK_SW(15, 16) TK_SW(14, 15)    \
  TK_SW(13, 14) TK_SW(12, 13) TK_SW(11, 12) TK_SW(10, 11) TK_SW(9, 10)     \
  TK_SW(8, 9) TK_SW(7, 8) TK_SW(6, 7) TK_SW(5, 6) TK_SW(4, 5)              \
  TK_SW(3, 4) TK_SW(2, 3) TK_SW(1, 2) TK_SW(0, 1)

__global__ __launch_bounds__(128, 4) void merge_kernel(
    const float* __restrict__ cd, const int* __restrict__ ci,
    int* __restrict__ idxf) {
  const int b = blockIdx.y;
  const int n = blockIdx.x * 128 + threadIdx.x;

  TK_LIST(TK_DECL)

  for (int ch = 0; ch < NCH; ++ch) {
    const size_t base = ((size_t)(b * NCH + ch) * KNN) * NN + n;
    for (int s = 0; s < KNN; ++s) {
      const float d = cd[base + (size_t)s * NN];
      const int j = ci[base + (size_t)s * NN];
      if ((d < td19) || ((d == td19) && (j < ti19))) {
        td19 = d;
        ti19 = j;
        TK_BUBBLE
      }
    }
  }

#define TK_STI(k) idxf[((size_t)b * KNN + (k)) * NN + n] = ti##k;
  TK_LIST(TK_STI)
#undef TK_STI
}

// ---------------------------------------------------------------------------
// Kernel 4: gather + max + leaky + transposed store (bf16 A).
// ---------------------------------------------------------------------------
__global__ __launch_bounds__(128) void gather_kernel(
    const unsigned short* __restrict__ Ab16, const float* __restrict__ Q,
    const int* __restrict__ idxf, float* __restrict__ out) {
  __shared__ int jidx[KNN][32];
  __shared__ float ob[32][OO + 1];

  const int b = blockIdx.y;
  const int n0 = blockIdx.x * 32;
  const int t = threadIdx.x;

  for (int e = t; e < KNN * 32; e += 128) {
    const int k = e >> 5, ii = e & 31;
    jidx[k][ii] = idxf[((size_t)b * KNN + k) * NN + n0 + ii];
  }
  __syncthreads();

  const unsigned short* Ab = Ab16 + (size_t)b * NN * OO;
  const float* Qb = Q + (size_t)b * NN * OO;

  for (int ii = 0; ii < 32; ++ii) {
    float m = -1e30f;
#pragma unroll
    for (int k = 0; k < KNN; ++k) {
      const unsigned v = Ab[(size_t)jidx[k][ii] * OO + t];
      m = fmaxf(m, __uint_as_float(v << 16));
    }
    const float h = m + Qb[(size_t)(n0 + ii) * OO + t];
    ob[ii][t] = (h >= 0.f) ? h : 0.2f * h;
  }
  __syncthreads();

  float* ou = out + (size_t)b * OO * NN;
  for (int e = t; e < 32 * OO; e += 128) {
    const int ii = e & 31, oo = e >> 5;
    ou[(size_t)oo * NN + n0 + ii] = ob[ii][oo];
  }
}

// ---------------------------------------------------------------------------
extern "C" void kernel_launch(void* const* d_in, const int* in_sizes, int n_in,
                              void* d_out, int out_size, void* d_ws,
                              size_t ws_size, hipStream_t stream) {
  (void)in_sizes;
  (void)n_in;
  (void)out_size;
  (void)ws_size;
  const float* x = (const float*)d_in[0];
  const float* W = (const float*)d_in[1];
  const float* bias = (const float*)d_in[2];
  float* out = (float*)d_out;

  char* ws = (char*)d_ws;
  size_t off = 0;
  unsigned short* Ab16 = (unsigned short*)(ws + off);
  off += (size_t)BB * NN * OO * 2;              // 8 MB
  float* Q = (float*)(ws + off);
  off += (size_t)BB * NN * OO * 4;              // 16 MB
  float* xsq = (float*)(ws + off);
  off += (size_t)BB * NN * 4;                   // 128 KB
  unsigned short* xsp = (unsigned short*)(ws + off);
  off += (size_t)BB * NN * SPLITW * 2;          // 12.6 MB
  float* cd = (float*)(ws + off);
  off += (size_t)BB * NCH * KNN * NN * 4;       // 10.5 MB
  int* ci = (int*)(ws + off);
  off += (size_t)BB * NCH * KNN * NN * 4;       // 10.5 MB
  int* idxf = (int*)(ws + off);
  off += (size_t)BB * KNN * NN * 4;             // 2.6 MB

  precompute_kernel<<<dim3(NN / 128, BB), 128, 0, stream>>>(x, W, bias, Ab16,
                                                            Q, xsq, xsp);
  knn_kernel<<<dim3(NN / 64, BB), 256, 0, stream>>>(xsp, xsq, cd, ci);
  merge_kernel<<<dim3(NN / 128, BB), 128, 0, stream>>>(cd, ci, idxf);
  gather_kernel<<<dim3(NN / 32, BB), 128, 0, stream>>>(Ab16, Q, idxf, out);
}

// Round 5
// 602.336 us; speedup vs baseline: 1.2289x; 1.2289x over previous
//
#include <hip/hip_runtime.h>

#define BB 8
#define CC 64
#define OO 128
#define NN 4096
#define KNN 20
#define NT 256          // 16-j tiles per batch scan
#define NG 64           // 4-tile groups
#define NCH 4           // merge chunks = per-row col-classes (g)
#define RING 9          // per-lane LDS ring slots
#define TRIG 5          // drain when any lane cnt>=5 (growth <=4/tile -> <=8)
#define SPLITW 192      // xsp row: 64 bf16 h | 64 bf16 m | 64 bf16 l (384 B)
#define TILEB (16 * SPLITW * 2)  // 6144 B per 16-row B tile

typedef short bf16x8 __attribute__((ext_vector_type(8)));
typedef float f32x4 __attribute__((ext_vector_type(4)));
typedef const __attribute__((address_space(1))) unsigned int* gas_ptr;
typedef __attribute__((address_space(3))) unsigned int* las_ptr;

// ===========================================================================
// Top-20: UNSORTED slots + cached (kmax,kpos); kpos eviction + argmax tree.
// Proven R5-R16. NAMED SCALARS only (R2: no SROA).
// knn ledger: R17 barrier-lockstep 4-tile-group = 356us. R18 (2-tile grp,
// 52KB) -11%; R19 (j-split, 1024 blk) -30%; R20 (RT hoist + reorder) +-0;
// R21 (zero-barrier wave-private staging) -15% + 20ms outliers. knn is at a
// structural plateau -- restored R17 VERBATIM below, do not touch.
// R22 targets the ~330us non-knn component (never profiled):
//   precompute: og-split x2 blocks (halves the 16K-FMA serial wall).
//   gather: 256-thr, uint pair loads, 16 waves/CU (was 8 scalar-load waves).
// ===========================================================================
#define REP20(F, P) F(P,0) F(P,1) F(P,2) F(P,3) F(P,4) F(P,5) F(P,6) F(P,7) \
    F(P,8) F(P,9) F(P,10) F(P,11) F(P,12) F(P,13) F(P,14) F(P,15) F(P,16)   \
    F(P,17) F(P,18) F(P,19)

#define TS_DECL(P,k) float P##m##k = 1e30f; int P##p##k = -1;
#define TS_REPL(P,k)                                                        \
  { const bool _h = (P##kpos == (k));                                       \
    P##m##k = _h ? _d : P##m##k;                                            \
    P##p##k = _h ? _j : P##p##k; }

#define TS_N(vd, xd, va, xa, vb, xb)                                        \
  { const bool _g = (vb) > (va); vd = _g ? (vb) : (va); xd = _g ? (xb) : (xa); }

#define TS_TREE(P)                                                          \
  { float t0,t1,t2,t3,t4,t5,t6,t7,t8,t9; int y0,y1,y2,y3,y4,y5,y6,y7,y8,y9; \
    TS_N(t0,y0, P##m0,0,  P##m1,1)   TS_N(t1,y1, P##m2,2,  P##m3,3)         \
    TS_N(t2,y2, P##m4,4,  P##m5,5)   TS_N(t3,y3, P##m6,6,  P##m7,7)         \
    TS_N(t4,y4, P##m8,8,  P##m9,9)   TS_N(t5,y5, P##m10,10, P##m11,11)      \
    TS_N(t6,y6, P##m12,12, P##m13,13) TS_N(t7,y7, P##m14,14, P##m15,15)     \
    TS_N(t8,y8, P##m16,16, P##m17,17) TS_N(t9,y9, P##m18,18, P##m19,19)     \
    float u0,u1,u2,u3,u4; int z0,z1,z2,z3,z4;                               \
    TS_N(u0,z0, t0,y0, t1,y1) TS_N(u1,z1, t2,y2, t3,y3)                     \
    TS_N(u2,z2, t4,y4, t5,y5) TS_N(u3,z3, t6,y6, t7,y7)                     \
    TS_N(u4,z4, t8,y8, t9,y9)                                               \
    float w0,w1; int q0,q1;                                                 \
    TS_N(w0,q0, u0,z0, u1,z1) TS_N(w1,q1, u2,z2, u3,z3)                     \
    float e0; int r0;                                                       \
    TS_N(e0,r0, w0,q0, w1,q1)                                               \
    TS_N(P##kmax, P##kpos, e0,r0, u4,z4) }

#define TS_INS(P, dval, jval)                                               \
  { const float _d = (dval); const int _j = (jval);                         \
    REP20(TS_REPL, P)                                                       \
    TS_TREE(P) }

// row-threshold refresh: rt = min(kmax over the 4 lanes sharing myrow)
#define RT_UPDATE                                                           \
  { const int _s1 = __builtin_amdgcn_ds_swizzle(__float_as_int(A_kmax), 0x101F); \
    const float _m1 = fminf(A_kmax, __int_as_float(_s1));                   \
    const int _s2 = __builtin_amdgcn_ds_swizzle(__float_as_int(_m1), 0x201F); \
    rt = fminf(_m1, __int_as_float(_s2)); }

__device__ __forceinline__ unsigned rne_bf16(float f) {
  const unsigned u = __float_as_uint(f);
  return (u + 0x7fffu + ((u >> 16) & 1u)) >> 16;
}

// ---------------------------------------------------------------------------
// Kernel 1: per-point precompute, og-split x2 (R22).
// Block (bx, b): n-range (bx>>1)*128..+128, O-half (bx&1)*64..+64.
// Half 0 additionally writes xsq + xsp. x loads duplicated (L2/L3 resident).
// ---------------------------------------------------------------------------
__global__ __launch_bounds__(128, 3) void precompute_kernel(
    const float* __restrict__ x, const float* __restrict__ W,
    const float* __restrict__ bias, unsigned short* __restrict__ Ab16,
    float* __restrict__ Q, float* __restrict__ xsq,
    unsigned short* __restrict__ xsp) {
  const int b = blockIdx.y;
  const int half = blockIdx.x & 1;
  const int n = (blockIdx.x >> 1) * 128 + threadIdx.x;
  const float* xb = x + (size_t)b * CC * NN;

  float xr[CC];
  float sq = 0.f;
#pragma unroll
  for (int c = 0; c < CC; ++c) {
    xr[c] = xb[(size_t)c * NN + n];
    sq = fmaf(xr[c], xr[c], sq);
  }

  if (half == 0) {
    xsq[(size_t)b * NN + n] = sq;
    unsigned* srow = (unsigned*)(xsp + ((size_t)b * NN + n) * SPLITW);
#pragma unroll
    for (int c = 0; c < CC; c += 2) {
      const unsigned h0 = rne_bf16(xr[c]), h1 = rne_bf16(xr[c + 1]);
      const float r0 = xr[c] - __uint_as_float(h0 << 16);
      const float r1 = xr[c + 1] - __uint_as_float(h1 << 16);
      const unsigned m0 = rne_bf16(r0), m1 = rne_bf16(r1);
      const float s0 = r0 - __uint_as_float(m0 << 16);
      const float s1 = r1 - __uint_as_float(m1 << 16);
      const unsigned l0 = rne_bf16(s0), l1 = rne_bf16(s1);
      srow[c / 2] = h0 | (h1 << 16);
      srow[32 + c / 2] = m0 | (m1 << 16);
      srow[64 + c / 2] = l0 | (l1 << 16);
    }
  }

  unsigned short* Arow = Ab16 + ((size_t)b * NN + n) * OO;
  float* Qrow = Q + ((size_t)b * NN + n) * OO;

  const int og0 = half * 64;
  for (int og = og0; og < og0 + 64; og += 4) {
    float p[4] = {0.f, 0.f, 0.f, 0.f};
    float g[4] = {0.f, 0.f, 0.f, 0.f};
#pragma unroll
    for (int oo = 0; oo < 4; ++oo) {
      const float* wr = W + (size_t)(og + oo) * (2 * CC);
#pragma unroll
      for (int c = 0; c < CC; c += 4) {
        float4 w1 = *(const float4*)(wr + c);
        float4 w2 = *(const float4*)(wr + CC + c);
        p[oo] = fmaf(w1.x, xr[c], p[oo]);
        p[oo] = fmaf(w1.y, xr[c + 1], p[oo]);
        p[oo] = fmaf(w1.z, xr[c + 2], p[oo]);
        p[oo] = fmaf(w1.w, xr[c + 3], p[oo]);
        g[oo] = fmaf(w2.x, xr[c], g[oo]);
        g[oo] = fmaf(w2.y, xr[c + 1], g[oo]);
        g[oo] = fmaf(w2.z, xr[c + 2], g[oo]);
        g[oo] = fmaf(w2.w, xr[c + 3], g[oo]);
      }
    }
    const unsigned pa0 = rne_bf16(p[0]) | (rne_bf16(p[1]) << 16);
    const unsigned pa1 = rne_bf16(p[2]) | (rne_bf16(p[3]) << 16);
    *(uint2*)(Arow + og) = make_uint2(pa0, pa1);
    float4 qv = make_float4(g[0] - p[0] + bias[og + 0], g[1] - p[1] + bias[og + 1],
                            g[2] - p[2] + bias[og + 2], g[3] - p[3] + bias[og + 3]);
    *(float4*)(Qrow + og) = qv;
  }
}

// ---------------------------------------------------------------------------
// Kernel 2: MFMA Gram-matrix kNN, 4-tile-group async staging (R17 VERBATIM).
// Wave wv stages tile 4G+wv (6 x global_load_lds, 16B/lane). Swizzle: LDS
// slot s = k*64+lane holds global chunk at c*384 + q*16 + k*64 (proven R16
// mapping: slot = m*16 + r, bank = c*4+k, conflict-free fragment reads).
// ---------------------------------------------------------------------------
#define STAGEG(G, BUF)                                                      \
  { const char* tb = (const char*)xspB + (size_t)(4 * (G) + wv) * TILEB + gof; \
    char* lb = (char*)(BUF) + wv * 6144;                                    \
    __builtin_amdgcn_global_load_lds((gas_ptr)(const void*)(tb), (las_ptr)(void*)(lb), 16, 0, 0); \
    __builtin_amdgcn_global_load_lds((gas_ptr)(const void*)(tb + 64), (las_ptr)(void*)(lb + 1024), 16, 0, 0); \
    __builtin_amdgcn_global_load_lds((gas_ptr)(const void*)(tb + 128), (las_ptr)(void*)(lb + 2048), 16, 0, 0); \
    __builtin_amdgcn_global_load_lds((gas_ptr)(const void*)(tb + 192), (las_ptr)(void*)(lb + 3072), 16, 0, 0); \
    __builtin_amdgcn_global_load_lds((gas_ptr)(const void*)(tb + 256), (las_ptr)(void*)(lb + 4096), 16, 0, 0); \
    __builtin_amdgcn_global_load_lds((gas_ptr)(const void*)(tb + 320), (las_ptr)(void*)(lb + 5120), 16, 0, 0); }

// fragment reads from swizzled LDS: chunk m = q+4*o at byte m*256 + c*16
#define TILE_MFMA_L(LBUF, BUF)                                              \
  { const char* bb = (const char*)(LBUF) + c16;                             \
    const bf16x8 Bh0 = *(const bf16x8*)(bb + (q + 0) * 256);                \
    const bf16x8 Bh1 = *(const bf16x8*)(bb + (q + 4) * 256);                \
    const bf16x8 Bm0 = *(const bf16x8*)(bb + (q + 8) * 256);                \
    const bf16x8 Bm1 = *(const bf16x8*)(bb + (q + 12) * 256);               \
    const bf16x8 Bl0 = *(const bf16x8*)(bb + (q + 16) * 256);               \
    const bf16x8 Bl1 = *(const bf16x8*)(bb + (q + 20) * 256);               \
    f32x4 ac0 = {0.f, 0.f, 0.f, 0.f};                                       \
    f32x4 ac1 = {0.f, 0.f, 0.f, 0.f};                                       \
    f32x4 ac2 = {0.f, 0.f, 0.f, 0.f};                                       \
    f32x4 ac3 = {0.f, 0.f, 0.f, 0.f};                                       \
    ac0 = __builtin_amdgcn_mfma_f32_16x16x32_bf16(Ah0, Bh0, ac0, 0, 0, 0);  \
    ac1 = __builtin_amdgcn_mfma_f32_16x16x32_bf16(Ah1, Bh1, ac1, 0, 0, 0);  \
    ac2 = __builtin_amdgcn_mfma_f32_16x16x32_bf16(Ah0, Bm0, ac2, 0, 0, 0);  \
    ac3 = __builtin_amdgcn_mfma_f32_16x16x32_bf16(Ah1, Bm1, ac3, 0, 0, 0);  \
    ac0 = __builtin_amdgcn_mfma_f32_16x16x32_bf16(Am0, Bh0, ac0, 0, 0, 0);  \
    ac1 = __builtin_amdgcn_mfma_f32_16x16x32_bf16(Am1, Bh1, ac1, 0, 0, 0);  \
    ac2 = __builtin_amdgcn_mfma_f32_16x16x32_bf16(Ah0, Bl0, ac2, 0, 0, 0);  \
    ac3 = __builtin_amdgcn_mfma_f32_16x16x32_bf16(Ah1, Bl1, ac3, 0, 0, 0);  \
    ac0 = __builtin_amdgcn_mfma_f32_16x16x32_bf16(Al0, Bh0, ac0, 0, 0, 0);  \
    ac1 = __builtin_amdgcn_mfma_f32_16x16x32_bf16(Al1, Bh1, ac1, 0, 0, 0);  \
    ac2 = __builtin_amdgcn_mfma_f32_16x16x32_bf16(Am0, Bm0, ac2, 0, 0, 0);  \
    ac3 = __builtin_amdgcn_mfma_f32_16x16x32_bf16(Am1, Bm1, ac3, 0, 0, 0);  \
    const f32x4 acc = (ac0 + ac1) + (ac2 + ac3);                            \
    float* bw = &bounce[BUF][wv][0];                                        \
    bw[(q * 4 + 0) * 20 + c] = acc[0];                                      \
    bw[(q * 4 + 1) * 20 + c] = acc[1];                                      \
    bw[(q * 4 + 2) * 20 + c] = acc[2];                                      \
    bw[(q * 4 + 3) * 20 + c] = acc[3]; }

#define TILE_VALS(T, BUF)                                                   \
  const float* br = &bounce[BUF][wv][myrow * 20 + 4 * g];                   \
  const f32x4 dots = *(const f32x4*)br;                                     \
  const float4 xx = *(const float4*)(xsqb + (T) * 16 + 4 * g);              \
  const float d0 = fmaf(-2.f, dots[0], xx.x);                               \
  const float d1 = fmaf(-2.f, dots[1], xx.y);                               \
  const float d2 = fmaf(-2.f, dots[2], xx.z);                               \
  const float d3 = fmaf(-2.f, dots[3], xx.w);                               \
  const int jb = (T) * 16 + 4 * g;

#define TILE_SELF(T, BUF, K0, K1, K2, K3)                                   \
  { TILE_VALS(T, BUF)                                                       \
    A_m##K0 = d0; A_p##K0 = jb;                                             \
    A_m##K1 = d1; A_p##K1 = jb + 1;                                         \
    A_m##K2 = d2; A_p##K2 = jb + 2;                                         \
    A_m##K3 = d3; A_p##K3 = jb + 3; }

#define TILE_SEL(T, BUF)                                                    \
  { TILE_VALS(T, BUF)                                                       \
    if (d0 <= rt) { myring[cnt] = make_float2(d0, __int_as_float(jb)); ++cnt; } \
    if (d1 <= rt) { myring[cnt] = make_float2(d1, __int_as_float(jb + 1)); ++cnt; } \
    if (d2 <= rt) { myring[cnt] = make_float2(d2, __int_as_float(jb + 2)); ++cnt; } \
    if (d3 <= rt) { myring[cnt] = make_float2(d3, __int_as_float(jb + 3)); ++cnt; } \
    if (__ballot(cnt >= TRIG)) {                                            \
      for (int _k = 0; _k < cnt; ++_k) {                                    \
        const float2 e = myring[_k];                                        \
        if (e.x < A_kmax) { TS_INS(A_, e.x, __float_as_int(e.y)) }          \
      }                                                                     \
      cnt = 0;                                                              \
    }                                                                       \
    RT_UPDATE }

__global__ __launch_bounds__(256, 2) void knn_kernel(
    const unsigned short* __restrict__ xsp, const float* __restrict__ xsq,
    float* __restrict__ cd, int* __restrict__ ci) {
  __shared__ unsigned short Bbuf0[4 * TILEB / 2];  // 24 KB (even groups)
  __shared__ unsigned short Bbuf1[4 * TILEB / 2];  // 24 KB (odd groups)
  __shared__ float bounce[2][4][16 * 20];          // 10 KB
  __shared__ float2 ring[256][RING];               // 18 KB

  const int b = blockIdx.y;
  const int wv = threadIdx.x >> 6;
  const int lane = threadIdx.x & 63;
  const int q = lane >> 4;
  const int c = lane & 15;
  const int c16 = c * 16;
  const int gof = c * 384 + q * 16;  // staging source offset (k adds 64)
  const int ibase = blockIdx.x * 64 + wv * 16;
  const int myrow = q * 4 + (c & 3);
  const int g = c >> 2;
  const int isel = ibase + myrow;

  const unsigned short* xspB = xsp + (size_t)b * NN * SPLITW;
  const float* xsqb = xsq + (size_t)b * NN;

  // A fragments: rows ibase+c, k-slice quad*8 (+32 for k-chunk 1)
  const unsigned short* arow = xspB + (size_t)(ibase + c) * SPLITW + q * 8;
  const bf16x8 Ah0 = *(const bf16x8*)(arow);
  const bf16x8 Ah1 = *(const bf16x8*)(arow + 32);
  const bf16x8 Am0 = *(const bf16x8*)(arow + 64);
  const bf16x8 Am1 = *(const bf16x8*)(arow + 96);
  const bf16x8 Al0 = *(const bf16x8*)(arow + 128);
  const bf16x8 Al1 = *(const bf16x8*)(arow + 160);

  REP20(TS_DECL, A_)
  float A_kmax = 1e30f; int A_kpos = 0;
  float rt = 1e30f;
  float2* myring = ring[threadIdx.x];
  int cnt = 0;

  // ---- prologue ----
  STAGEG(0, Bbuf0)
  __syncthreads();
  // group 0: tiles 0..3 from Bbuf0; stage group 1
  STAGEG(1, Bbuf1)
  TILE_MFMA_L(Bbuf0 + 0 * 3072, 0)
  TILE_MFMA_L(Bbuf0 + 1 * 3072, 1) TILE_SELF(0, 0, 0, 1, 2, 3)
  TILE_MFMA_L(Bbuf0 + 2 * 3072, 0) TILE_SELF(1, 1, 4, 5, 6, 7)
  TILE_MFMA_L(Bbuf0 + 3 * 3072, 1) TILE_SELF(2, 0, 8, 9, 10, 11)
  __syncthreads();
  // group 1: tiles 4..7 from Bbuf1; stage group 2
  STAGEG(2, Bbuf0)
  TILE_MFMA_L(Bbuf1 + 0 * 3072, 0) TILE_SELF(3, 1, 12, 13, 14, 15)
  TILE_MFMA_L(Bbuf1 + 1 * 3072, 1) TILE_SELF(4, 0, 16, 17, 18, 19)
  TS_TREE(A_)
  RT_UPDATE
  TILE_MFMA_L(Bbuf1 + 2 * 3072, 0) TILE_SEL(5, 1)
  TILE_MFMA_L(Bbuf1 + 3 * 3072, 1) TILE_SEL(6, 0)
  __syncthreads();

  // ---- steady state: groups 2..62 ----
  for (int G = 2; G < NG - 1; ++G) {
    unsigned short* cur = (G & 1) ? Bbuf1 : Bbuf0;
    unsigned short* nxt = (G & 1) ? Bbuf0 : Bbuf1;
    STAGEG(G + 1, nxt)
    const int t0 = 4 * G;
    TILE_MFMA_L(cur + 0 * 3072, 0) TILE_SEL(t0 - 1, 1)
    TILE_MFMA_L(cur + 1 * 3072, 1) TILE_SEL(t0, 0)
    TILE_MFMA_L(cur + 2 * 3072, 0) TILE_SEL(t0 + 1, 1)
    TILE_MFMA_L(cur + 3 * 3072, 1) TILE_SEL(t0 + 2, 0)
    __syncthreads();
  }

  // ---- epilogue: group 63 (tiles 252..255 in Bbuf1), no staging ----
  TILE_MFMA_L(Bbuf1 + 0 * 3072, 0) TILE_SEL(251, 1)
  TILE_MFMA_L(Bbuf1 + 1 * 3072, 1) TILE_SEL(252, 0)
  TILE_MFMA_L(Bbuf1 + 2 * 3072, 0) TILE_SEL(253, 1)
  TILE_MFMA_L(Bbuf1 + 3 * 3072, 1) TILE_SEL(254, 0)
  TILE_SEL(255, 1)

  // final drain
  for (int _k = 0; _k < cnt; ++_k) {
    const float2 e = myring[_k];
    if (e.x < A_kmax) { TS_INS(A_, e.x, __float_as_int(e.y)) }
  }

  const size_t base = ((size_t)(b * NCH + g) * KNN) * NN + isel;
#define TS_ST(P,k) cd[base + (size_t)(k) * NN] = P##m##k; \
                   ci[base + (size_t)(k) * NN] = P##p##k;
  REP20(TS_ST, A_)
#undef TS_ST
}

// ---------------------------------------------------------------------------
// Kernel 3: merge NCH=4 unsorted 20-lists (lex (d, j) compare — exact jax).
// ---------------------------------------------------------------------------
#define TK_LIST(OP) OP(0) OP(1) OP(2) OP(3) OP(4) OP(5) OP(6) OP(7) OP(8) \
    OP(9) OP(10) OP(11) OP(12) OP(13) OP(14) OP(15) OP(16) OP(17) OP(18) OP(19)
#define TK_DECL(k) float td##k = 1e30f; int ti##k = -1;
#define TK_SW(a, b)                                                        \
  {                                                                        \
    const bool _s = (td##b < td##a) ||                                     \
                    ((td##b == td##a) && (ti##b < ti##a));                 \
    const float _fa = _s ? td##b : td##a;                                  \
    const float _fb = _s ? td##a : td##b;                                  \
    const int _ia = _s ? ti##b : ti##a;                                    \
    const int _ib = _s ? ti##a : ti##b;                                    \
    td##a = _fa; td##b = _fb; ti##a = _ia; ti##b = _ib;                    \
  }
#define TK_BUBBLE                                                          \
  TK_SW(18, 19) TK_SW(17, 18) TK_SW(16, 17) TK_SW(15, 16) TK_SW(14, 15)    \
  TK_SW(13, 14) TK_SW(12, 13) TK_SW(11, 12) TK_SW(10, 11) TK_SW(9, 10)     \
  TK_SW(8, 9) TK_SW(7, 8) TK_SW(6, 7) TK_SW(5, 6) TK_SW(4, 5)              \
  TK_SW(3, 4) TK_SW(2, 3) TK_SW(1, 2) TK_SW(0, 1)

__global__ __launch_bounds__(128, 4) void merge_kernel(
    const float* __restrict__ cd, const int* __restrict__ ci,
    int* __restrict__ idxf) {
  const int b = blockIdx.y;
  const int n = blockIdx.x * 128 + threadIdx.x;

  TK_LIST(TK_DECL)

  for (int ch = 0; ch < NCH; ++ch) {
    const size_t base = ((size_t)(b * NCH + ch) * KNN) * NN + n;
    for (int s = 0; s < KNN; ++s) {
      const float d = cd[base + (size_t)s * NN];
      const int j = ci[base + (size_t)s * NN];
      if ((d < td19) || ((d == td19) && (j < ti19))) {
        td19 = d;
        ti19 = j;
        TK_BUBBLE
      }
    }
  }

#define TK_STI(k) idxf[((size_t)b * KNN + (k)) * NN + n] = ti##k;
  TK_LIST(TK_STI)
#undef TK_STI
}

// ---------------------------------------------------------------------------
// Kernel 4: gather + max + leaky + transposed store (R22 rewrite).
// 256 threads: p = t&63 -> channel pair (2p, 2p+1); h = t>>6 -> ii octet.
// uint loads (2 bf16 each) halve the load count; 4 waves/block x 4 blocks/CU
// = 16 waves/CU to hide L2/L3 gather latency (was 8 waves, scalar u16).
// ---------------------------------------------------------------------------
__global__ __launch_bounds__(256) void gather_kernel(
    const unsigned short* __restrict__ Ab16, const float* __restrict__ Q,
    const int* __restrict__ idxf, float* __restrict__ out) {
  __shared__ int jidx[KNN][32];
  __shared__ float ob[32][OO + 2];

  const int b = blockIdx.y;
  const int n0 = blockIdx.x * 32;
  const int t = threadIdx.x;
  const int p = t & 63;
  const int h = t >> 6;

  for (int e = t; e < KNN * 32; e += 256) {
    const int k = e >> 5, ii = e & 31;
    jidx[k][ii] = idxf[((size_t)b * KNN + k) * NN + n0 + ii];
  }
  __syncthreads();

  const unsigned short* Ab = Ab16 + (size_t)b * NN * OO;
  const float* Qb = Q + (size_t)b * NN * OO;

  for (int ii = h * 8; ii < h * 8 + 8; ++ii) {
    float m0 = -1e30f, m1 = -1e30f;
#pragma unroll
    for (int k = 0; k < KNN; ++k) {
      const unsigned v =
          *(const unsigned*)(Ab + (size_t)jidx[k][ii] * OO + 2 * p);
      m0 = fmaxf(m0, __uint_as_float(v << 16));
      m1 = fmaxf(m1, __uint_as_float(v & 0xFFFF0000u));
    }
    const float2 qv = *(const float2*)(Qb + (size_t)(n0 + ii) * OO + 2 * p);
    const float h0 = m0 + qv.x;
    const float h1 = m1 + qv.y;
    ob[ii][2 * p] = (h0 >= 0.f) ? h0 : 0.2f * h0;
    ob[ii][2 * p + 1] = (h1 >= 0.f) ? h1 : 0.2f * h1;
  }
  __syncthreads();

  float* ou = out + (size_t)b * OO * NN;
  for (int e = t; e < 32 * OO; e += 256) {
    const int ii = e & 31, oo = e >> 5;
    ou[(size_t)oo * NN + n0 + ii] = ob[ii][oo];
  }
}

// ---------------------------------------------------------------------------
extern "C" void kernel_launch(void* const* d_in, const int* in_sizes, int n_in,
                              void* d_out, int out_size, void* d_ws,
                              size_t ws_size, hipStream_t stream) {
  (void)in_sizes;
  (void)n_in;
  (void)out_size;
  (void)ws_size;
  const float* x = (const float*)d_in[0];
  const float* W = (const float*)d_in[1];
  const float* bias = (const float*)d_in[2];
  float* out = (float*)d_out;

  char* ws = (char*)d_ws;
  size_t off = 0;
  unsigned short* Ab16 = (unsigned short*)(ws + off);
  off += (size_t)BB * NN * OO * 2;              // 8 MB
  float* Q = (float*)(ws + off);
  off += (size_t)BB * NN * OO * 4;              // 16 MB
  float* xsq = (float*)(ws + off);
  off += (size_t)BB * NN * 4;                   // 128 KB
  unsigned short* xsp = (unsigned short*)(ws + off);
  off += (size_t)BB * NN * SPLITW * 2;          // 12.6 MB
  float* cd = (float*)(ws + off);
  off += (size_t)BB * NCH * KNN * NN * 4;       // 10.5 MB
  int* ci = (int*)(ws + off);
  off += (size_t)BB * NCH * KNN * NN * 4;       // 10.5 MB
  int* idxf = (int*)(ws + off);
  off += (size_t)BB * KNN * NN * 4;             // 2.6 MB

  precompute_kernel<<<dim3(2 * (NN / 128), BB), 128, 0, stream>>>(
      x, W, bias, Ab16, Q, xsq, xsp);
  knn_kernel<<<dim3(NN / 64, BB), 256, 0, stream>>>(xsp, xsq, cd, ci);
  merge_kernel<<<dim3(NN / 128, BB), 128, 0, stream>>>(cd, ci, idxf);
  gather_kernel<<<dim3(NN / 32, BB), 256, 0, stream>>>(Ab16, Q, idxf, out);
}

// Round 7
// 533.952 us; speedup vs baseline: 1.3863x; 1.1281x over previous
//
#include <hip/hip_runtime.h>

#define BB 8
#define CC 64
#define OO 128
#define NN 4096
#define KNN 20
#define NT 256          // 16-j tiles per batch scan
#define NG 64           // 4-tile groups
#define NCH 4           // merge chunks = per-row col-classes (g)
#define RING 9          // per-lane LDS ring slots
#define TRIG 5          // drain when any lane cnt>=5 (growth <=4/tile -> <=8)
#define SPLITW 192      // xsp row: 64 bf16 h | 64 bf16 m | 64 bf16 l (384 B)
#define WSPL 384        // Wsp row: 128 bf16 h | 128 m | 128 l (768 B)
#define TILEB (16 * SPLITW * 2)  // 6144 B per 16-row B tile

typedef short bf16x8 __attribute__((ext_vector_type(8)));
typedef float f32x4 __attribute__((ext_vector_type(4)));
typedef const __attribute__((address_space(1))) unsigned int* gas_ptr;
typedef __attribute__((address_space(3))) unsigned int* las_ptr;

// ===========================================================================
// knn ledger: R17 barrier-lockstep = 356us; R18 -11%, R19 -30%, R20 +-0,
// R21 -15% => structural plateau, knn kept VERBATIM (do not touch).
// R22 (WIN, -86us): og-split precompute + uint-pair gather => the ~256us
// non-knn component is real kernel time. Theory: old precompute is L1-BW
// bound -- W loads are lane-uniform but issued as vector loads (2MB/wave
// through L1). R23: replace the p/g FMA loop with the PROVEN 3-split MFMA
// pattern (same 6 products as knn): wsplit (W->h/m/l bf16, 96KB) +
// aq_kernel (A=rne_bf16(p), Q=g-p+bias via 24 MFMA per 16x16 o-tile).
// 6.4 GFLOP total -> ~15us vs the ~100+us VALU/L1 wall. xprep keeps only
// xsq+xsp. Numerics: 3-split err ~1e-5 abs; absmax bound 0.03125+2e-5.
// (R24 = R23 resubmitted verbatim: container-acquisition infra failure.)
// ===========================================================================
#define REP20(F, P) F(P,0) F(P,1) F(P,2) F(P,3) F(P,4) F(P,5) F(P,6) F(P,7) \
    F(P,8) F(P,9) F(P,10) F(P,11) F(P,12) F(P,13) F(P,14) F(P,15) F(P,16)   \
    F(P,17) F(P,18) F(P,19)

#define TS_DECL(P,k) float P##m##k = 1e30f; int P##p##k = -1;
#define TS_REPL(P,k)                                                        \
  { const bool _h = (P##kpos == (k));                                       \
    P##m##k = _h ? _d : P##m##k;                                            \
    P##p##k = _h ? _j : P##p##k; }

#define TS_N(vd, xd, va, xa, vb, xb)                                        \
  { const bool _g = (vb) > (va); vd = _g ? (vb) : (va); xd = _g ? (xb) : (xa); }

#define TS_TREE(P)                                                          \
  { float t0,t1,t2,t3,t4,t5,t6,t7,t8,t9; int y0,y1,y2,y3,y4,y5,y6,y7,y8,y9; \
    TS_N(t0,y0, P##m0,0,  P##m1,1)   TS_N(t1,y1, P##m2,2,  P##m3,3)         \
    TS_N(t2,y2, P##m4,4,  P##m5,5)   TS_N(t3,y3, P##m6,6,  P##m7,7)         \
    TS_N(t4,y4, P##m8,8,  P##m9,9)   TS_N(t5,y5, P##m10,10, P##m11,11)      \
    TS_N(t6,y6, P##m12,12, P##m13,13) TS_N(t7,y7, P##m14,14, P##m15,15)     \
    TS_N(t8,y8, P##m16,16, P##m17,17) TS_N(t9,y9, P##m18,18, P##m19,19)     \
    float u0,u1,u2,u3,u4; int z0,z1,z2,z3,z4;                               \
    TS_N(u0,z0, t0,y0, t1,y1) TS_N(u1,z1, t2,y2, t3,y3)                     \
    TS_N(u2,z2, t4,y4, t5,y5) TS_N(u3,z3, t6,y6, t7,y7)                     \
    TS_N(u4,z4, t8,y8, t9,y9)                                               \
    float w0,w1; int q0,q1;                                                 \
    TS_N(w0,q0, u0,z0, u1,z1) TS_N(w1,q1, u2,z2, u3,z3)                     \
    float e0; int r0;                                                       \
    TS_N(e0,r0, w0,q0, w1,q1)                                               \
    TS_N(P##kmax, P##kpos, e0,r0, u4,z4) }

#define TS_INS(P, dval, jval)                                               \
  { const float _d = (dval); const int _j = (jval);                         \
    REP20(TS_REPL, P)                                                       \
    TS_TREE(P) }

// row-threshold refresh: rt = min(kmax over the 4 lanes sharing myrow)
#define RT_UPDATE                                                           \
  { const int _s1 = __builtin_amdgcn_ds_swizzle(__float_as_int(A_kmax), 0x101F); \
    const float _m1 = fminf(A_kmax, __int_as_float(_s1));                   \
    const int _s2 = __builtin_amdgcn_ds_swizzle(__float_as_int(_m1), 0x201F); \
    rt = fminf(_m1, __int_as_float(_s2)); }

__device__ __forceinline__ unsigned rne_bf16(float f) {
  const unsigned u = __float_as_uint(f);
  return (u + 0x7fffu + ((u >> 16) & 1u)) >> 16;
}

// ---------------------------------------------------------------------------
// Kernel 1a: W -> h/m/l bf16 split (one-time, 96 KB output).
// ---------------------------------------------------------------------------
__global__ __launch_bounds__(128) void wsplit_kernel(
    const float* __restrict__ W, unsigned short* __restrict__ Wsp) {
  const int o = blockIdx.x;      // 128 rows
  const int t = threadIdx.x;     // 128 cols
  const float w = W[(size_t)o * (2 * CC) + t];
  const unsigned h = rne_bf16(w);
  const float r = w - __uint_as_float(h << 16);
  const unsigned m = rne_bf16(r);
  const float s = r - __uint_as_float(m << 16);
  const unsigned l = rne_bf16(s);
  unsigned short* row = Wsp + (size_t)o * WSPL;
  row[t] = (unsigned short)h;
  row[128 + t] = (unsigned short)m;
  row[256 + t] = (unsigned short)l;
}

// ---------------------------------------------------------------------------
// Kernel 1b: per-point xsq + 3-split xsp (light; exact same values as R22).
// ---------------------------------------------------------------------------
__global__ __launch_bounds__(128, 3) void xprep_kernel(
    const float* __restrict__ x, float* __restrict__ xsq,
    unsigned short* __restrict__ xsp) {
  const int b = blockIdx.y;
  const int n = blockIdx.x * 128 + threadIdx.x;
  const float* xb = x + (size_t)b * CC * NN;

  float xr[CC];
  float sq = 0.f;
#pragma unroll
  for (int c = 0; c < CC; ++c) {
    xr[c] = xb[(size_t)c * NN + n];
    sq = fmaf(xr[c], xr[c], sq);
  }
  xsq[(size_t)b * NN + n] = sq;

  unsigned* srow = (unsigned*)(xsp + ((size_t)b * NN + n) * SPLITW);
#pragma unroll
  for (int c = 0; c < CC; c += 2) {
    const unsigned h0 = rne_bf16(xr[c]), h1 = rne_bf16(xr[c + 1]);
    const float r0 = xr[c] - __uint_as_float(h0 << 16);
    const float r1 = xr[c + 1] - __uint_as_float(h1 << 16);
    const unsigned m0 = rne_bf16(r0), m1 = rne_bf16(r1);
    const float s0 = r0 - __uint_as_float(m0 << 16);
    const float s1 = r1 - __uint_as_float(m1 << 16);
    const unsigned l0 = rne_bf16(s0), l1 = rne_bf16(s1);
    srow[c / 2] = h0 | (h1 << 16);
    srow[32 + c / 2] = m0 | (m1 << 16);
    srow[64 + c / 2] = l0 | (l1 << 16);
  }
}

// ---------------------------------------------------------------------------
// Kernel 1c: A/Q via 3-split MFMA (knn's proven 6-product pattern).
// Wave = 16 n-rows; loop 8 o-tiles of 16. D row=(lane>>4)*4+i, col=lane&15.
// A-frag: xsp row nb+c, k-slice q*8 (identical to knn A-frags).
// B-frag: Wsp row ot*16+c; p uses W cols 0..63, g uses 64..127.
// ---------------------------------------------------------------------------
#define MFMA6(ACC, B0, B1, B2, B3, B4, B5)                                  \
  f32x4 ACC;                                                                \
  { f32x4 a0 = {0.f,0.f,0.f,0.f}; f32x4 a1 = {0.f,0.f,0.f,0.f};             \
    f32x4 a2 = {0.f,0.f,0.f,0.f}; f32x4 a3 = {0.f,0.f,0.f,0.f};             \
    a0 = __builtin_amdgcn_mfma_f32_16x16x32_bf16(Ah0, B0, a0, 0, 0, 0);     \
    a1 = __builtin_amdgcn_mfma_f32_16x16x32_bf16(Ah1, B1, a1, 0, 0, 0);     \
    a2 = __builtin_amdgcn_mfma_f32_16x16x32_bf16(Ah0, B2, a2, 0, 0, 0);     \
    a3 = __builtin_amdgcn_mfma_f32_16x16x32_bf16(Ah1, B3, a3, 0, 0, 0);     \
    a0 = __builtin_amdgcn_mfma_f32_16x16x32_bf16(Am0, B0, a0, 0, 0, 0);     \
    a1 = __builtin_amdgcn_mfma_f32_16x16x32_bf16(Am1, B1, a1, 0, 0, 0);     \
    a2 = __builtin_amdgcn_mfma_f32_16x16x32_bf16(Ah0, B4, a2, 0, 0, 0);     \
    a3 = __builtin_amdgcn_mfma_f32_16x16x32_bf16(Ah1, B5, a3, 0, 0, 0);     \
    a0 = __builtin_amdgcn_mfma_f32_16x16x32_bf16(Al0, B0, a0, 0, 0, 0);     \
    a1 = __builtin_amdgcn_mfma_f32_16x16x32_bf16(Al1, B1, a1, 0, 0, 0);     \
    a2 = __builtin_amdgcn_mfma_f32_16x16x32_bf16(Am0, B2, a2, 0, 0, 0);     \
    a3 = __builtin_amdgcn_mfma_f32_16x16x32_bf16(Am1, B3, a3, 0, 0, 0);     \
    ACC = (a0 + a1) + (a2 + a3); }

__global__ __launch_bounds__(256, 3) void aq_kernel(
    const unsigned short* __restrict__ xsp,
    const unsigned short* __restrict__ Wsp, const float* __restrict__ bias,
    unsigned short* __restrict__ Ab16, float* __restrict__ Q) {
  const int b = blockIdx.y;
  const int wv = threadIdx.x >> 6;
  const int lane = threadIdx.x & 63;
  const int q = lane >> 4;
  const int c = lane & 15;
  const int nb = blockIdx.x * 64 + wv * 16;

  // A fragments (same pattern as knn): rows nb+c, k-slice q*8
  const unsigned short* arow =
      xsp + ((size_t)b * NN + nb + c) * SPLITW + q * 8;
  const bf16x8 Ah0 = *(const bf16x8*)(arow);
  const bf16x8 Ah1 = *(const bf16x8*)(arow + 32);
  const bf16x8 Am0 = *(const bf16x8*)(arow + 64);
  const bf16x8 Am1 = *(const bf16x8*)(arow + 96);
  const bf16x8 Al0 = *(const bf16x8*)(arow + 128);
  const bf16x8 Al1 = *(const bf16x8*)(arow + 160);

  unsigned short* Ab = Ab16 + (size_t)b * NN * OO;
  float* Qb = Q + (size_t)b * NN * OO;

#pragma unroll 2
  for (int ot = 0; ot < 8; ++ot) {
    const unsigned short* wrow = Wsp + (size_t)(ot * 16 + c) * WSPL + q * 8;
    // p-part: W cols 0..63 (h/m/l at +0/+128/+256)
    const bf16x8 Ph0 = *(const bf16x8*)(wrow);
    const bf16x8 Ph1 = *(const bf16x8*)(wrow + 32);
    const bf16x8 Pm0 = *(const bf16x8*)(wrow + 128);
    const bf16x8 Pm1 = *(const bf16x8*)(wrow + 160);
    const bf16x8 Pl0 = *(const bf16x8*)(wrow + 256);
    const bf16x8 Pl1 = *(const bf16x8*)(wrow + 288);
    MFMA6(accP, Ph0, Ph1, Pm0, Pm1, Pl0, Pl1)
    // g-part: W cols 64..127
    const bf16x8 Gh0 = *(const bf16x8*)(wrow + 64);
    const bf16x8 Gh1 = *(const bf16x8*)(wrow + 96);
    const bf16x8 Gm0 = *(const bf16x8*)(wrow + 192);
    const bf16x8 Gm1 = *(const bf16x8*)(wrow + 224);
    const bf16x8 Gl0 = *(const bf16x8*)(wrow + 320);
    const bf16x8 Gl1 = *(const bf16x8*)(wrow + 352);
    MFMA6(accG, Gh0, Gh1, Gm0, Gm1, Gl0, Gl1)

    const float bv = bias[ot * 16 + c];
#pragma unroll
    for (int i = 0; i < 4; ++i) {
      const size_t row = (size_t)(nb + q * 4 + i);
      const float p = accP[i];
      Ab[row * OO + ot * 16 + c] = (unsigned short)rne_bf16(p);
      Qb[row * OO + ot * 16 + c] = accG[i] - p + bv;
    }
  }
}

// ---------------------------------------------------------------------------
// Kernel 2: MFMA Gram-matrix kNN, 4-tile-group async staging (R17 VERBATIM).
// ---------------------------------------------------------------------------
#define STAGEG(G, BUF)                                                      \
  { const char* tb = (const char*)xspB + (size_t)(4 * (G) + wv) * TILEB + gof; \
    char* lb = (char*)(BUF) + wv * 6144;                                    \
    __builtin_amdgcn_global_load_lds((gas_ptr)(const void*)(tb), (las_ptr)(void*)(lb), 16, 0, 0); \
    __builtin_amdgcn_global_load_lds((gas_ptr)(const void*)(tb + 64), (las_ptr)(void*)(lb + 1024), 16, 0, 0); \
    __builtin_amdgcn_global_load_lds((gas_ptr)(const void*)(tb + 128), (las_ptr)(void*)(lb + 2048), 16, 0, 0); \
    __builtin_amdgcn_global_load_lds((gas_ptr)(const void*)(tb + 192), (las_ptr)(void*)(lb + 3072), 16, 0, 0); \
    __builtin_amdgcn_global_load_lds((gas_ptr)(const void*)(tb + 256), (las_ptr)(void*)(lb + 4096), 16, 0, 0); \
    __builtin_amdgcn_global_load_lds((gas_ptr)(const void*)(tb + 320), (las_ptr)(void*)(lb + 5120), 16, 0, 0); }

#define TILE_MFMA_L(LBUF, BUF)                                              \
  { const char* bb = (const char*)(LBUF) + c16;                             \
    const bf16x8 Bh0 = *(const bf16x8*)(bb + (q + 0) * 256);                \
    const bf16x8 Bh1 = *(const bf16x8*)(bb + (q + 4) * 256);                \
    const bf16x8 Bm0 = *(const bf16x8*)(bb + (q + 8) * 256);                \
    const bf16x8 Bm1 = *(const bf16x8*)(bb + (q + 12) * 256);               \
    const bf16x8 Bl0 = *(const bf16x8*)(bb + (q + 16) * 256);               \
    const bf16x8 Bl1 = *(const bf16x8*)(bb + (q + 20) * 256);               \
    f32x4 ac0 = {0.f, 0.f, 0.f, 0.f};                                       \
    f32x4 ac1 = {0.f, 0.f, 0.f, 0.f};                                       \
    f32x4 ac2 = {0.f, 0.f, 0.f, 0.f};                                       \
    f32x4 ac3 = {0.f, 0.f, 0.f, 0.f};                                       \
    ac0 = __builtin_amdgcn_mfma_f32_16x16x32_bf16(Ah0, Bh0, ac0, 0, 0, 0);  \
    ac1 = __builtin_amdgcn_mfma_f32_16x16x32_bf16(Ah1, Bh1, ac1, 0, 0, 0);  \
    ac2 = __builtin_amdgcn_mfma_f32_16x16x32_bf16(Ah0, Bm0, ac2, 0, 0, 0);  \
    ac3 = __builtin_amdgcn_mfma_f32_16x16x32_bf16(Ah1, Bm1, ac3, 0, 0, 0);  \
    ac0 = __builtin_amdgcn_mfma_f32_16x16x32_bf16(Am0, Bh0, ac0, 0, 0, 0);  \
    ac1 = __builtin_amdgcn_mfma_f32_16x16x32_bf16(Am1, Bh1, ac1, 0, 0, 0);  \
    ac2 = __builtin_amdgcn_mfma_f32_16x16x32_bf16(Ah0, Bl0, ac2, 0, 0, 0);  \
    ac3 = __builtin_amdgcn_mfma_f32_16x16x32_bf16(Ah1, Bl1, ac3, 0, 0, 0);  \
    ac0 = __builtin_amdgcn_mfma_f32_16x16x32_bf16(Al0, Bh0, ac0, 0, 0, 0);  \
    ac1 = __builtin_amdgcn_mfma_f32_16x16x32_bf16(Al1, Bh1, ac1, 0, 0, 0);  \
    ac2 = __builtin_amdgcn_mfma_f32_16x16x32_bf16(Am0, Bm0, ac2, 0, 0, 0);  \
    ac3 = __builtin_amdgcn_mfma_f32_16x16x32_bf16(Am1, Bm1, ac3, 0, 0, 0);  \
    const f32x4 acc = (ac0 + ac1) + (ac2 + ac3);                            \
    float* bw = &bounce[BUF][wv][0];                                        \
    bw[(q * 4 + 0) * 20 + c] = acc[0];                                      \
    bw[(q * 4 + 1) * 20 + c] = acc[1];                                      \
    bw[(q * 4 + 2) * 20 + c] = acc[2];                                      \
    bw[(q * 4 + 3) * 20 + c] = acc[3]; }

#define TILE_VALS(T, BUF)                                                   \
  const float* br = &bounce[BUF][wv][myrow * 20 + 4 * g];                   \
  const f32x4 dots = *(const f32x4*)br;                                     \
  const float4 xx = *(const float4*)(xsqb + (T) * 16 + 4 * g);              \
  const float d0 = fmaf(-2.f, dots[0], xx.x);                               \
  const float d1 = fmaf(-2.f, dots[1], xx.y);                               \
  const float d2 = fmaf(-2.f, dots[2], xx.z);                               \
  const float d3 = fmaf(-2.f, dots[3], xx.w);                               \
  const int jb = (T) * 16 + 4 * g;

#define TILE_SELF(T, BUF, K0, K1, K2, K3)                                   \
  { TILE_VALS(T, BUF)                                                       \
    A_m##K0 = d0; A_p##K0 = jb;                                             \
    A_m##K1 = d1; A_p##K1 = jb + 1;                                         \
    A_m##K2 = d2; A_p##K2 = jb + 2;                                         \
    A_m##K3 = d3; A_p##K3 = jb + 3; }

#define TILE_SEL(T, BUF)                                                    \
  { TILE_VALS(T, BUF)                                                       \
    if (d0 <= rt) { myring[cnt] = make_float2(d0, __int_as_float(jb)); ++cnt; } \
    if (d1 <= rt) { myring[cnt] = make_float2(d1, __int_as_float(jb + 1)); ++cnt; } \
    if (d2 <= rt) { myring[cnt] = make_float2(d2, __int_as_float(jb + 2)); ++cnt; } \
    if (d3 <= rt) { myring[cnt] = make_float2(d3, __int_as_float(jb + 3)); ++cnt; } \
    if (__ballot(cnt >= TRIG)) {                                            \
      for (int _k = 0; _k < cnt; ++_k) {                                    \
        const float2 e = myring[_k];                                        \
        if (e.x < A_kmax) { TS_INS(A_, e.x, __float_as_int(e.y)) }          \
      }                                                                     \
      cnt = 0;                                                              \
    }                                                                       \
    RT_UPDATE }

__global__ __launch_bounds__(256, 2) void knn_kernel(
    const unsigned short* __restrict__ xsp, const float* __restrict__ xsq,
    float* __restrict__ cd, int* __restrict__ ci) {
  __shared__ unsigned short Bbuf0[4 * TILEB / 2];  // 24 KB (even groups)
  __shared__ unsigned short Bbuf1[4 * TILEB / 2];  // 24 KB (odd groups)
  __shared__ float bounce[2][4][16 * 20];          // 10 KB
  __shared__ float2 ring[256][RING];               // 18 KB

  const int b = blockIdx.y;
  const int wv = threadIdx.x >> 6;
  const int lane = threadIdx.x & 63;
  const int q = lane >> 4;
  const int c = lane & 15;
  const int c16 = c * 16;
  const int gof = c * 384 + q * 16;  // staging source offset (k adds 64)
  const int ibase = blockIdx.x * 64 + wv * 16;
  const int myrow = q * 4 + (c & 3);
  const int g = c >> 2;
  const int isel = ibase + myrow;

  const unsigned short* xspB = xsp + (size_t)b * NN * SPLITW;
  const float* xsqb = xsq + (size_t)b * NN;

  // A fragments: rows ibase+c, k-slice quad*8 (+32 for k-chunk 1)
  const unsigned short* arow = xspB + (size_t)(ibase + c) * SPLITW + q * 8;
  const bf16x8 Ah0 = *(const bf16x8*)(arow);
  const bf16x8 Ah1 = *(const bf16x8*)(arow + 32);
  const bf16x8 Am0 = *(const bf16x8*)(arow + 64);
  const bf16x8 Am1 = *(const bf16x8*)(arow + 96);
  const bf16x8 Al0 = *(const bf16x8*)(arow + 128);
  const bf16x8 Al1 = *(const bf16x8*)(arow + 160);

  REP20(TS_DECL, A_)
  float A_kmax = 1e30f; int A_kpos = 0;
  float rt = 1e30f;
  float2* myring = ring[threadIdx.x];
  int cnt = 0;

  // ---- prologue ----
  STAGEG(0, Bbuf0)
  __syncthreads();
  STAGEG(1, Bbuf1)
  TILE_MFMA_L(Bbuf0 + 0 * 3072, 0)
  TILE_MFMA_L(Bbuf0 + 1 * 3072, 1) TILE_SELF(0, 0, 0, 1, 2, 3)
  TILE_MFMA_L(Bbuf0 + 2 * 3072, 0) TILE_SELF(1, 1, 4, 5, 6, 7)
  TILE_MFMA_L(Bbuf0 + 3 * 3072, 1) TILE_SELF(2, 0, 8, 9, 10, 11)
  __syncthreads();
  STAGEG(2, Bbuf0)
  TILE_MFMA_L(Bbuf1 + 0 * 3072, 0) TILE_SELF(3, 1, 12, 13, 14, 15)
  TILE_MFMA_L(Bbuf1 + 1 * 3072, 1) TILE_SELF(4, 0, 16, 17, 18, 19)
  TS_TREE(A_)
  RT_UPDATE
  TILE_MFMA_L(Bbuf1 + 2 * 3072, 0) TILE_SEL(5, 1)
  TILE_MFMA_L(Bbuf1 + 3 * 3072, 1) TILE_SEL(6, 0)
  __syncthreads();

  // ---- steady state: groups 2..62 ----
  for (int G = 2; G < NG - 1; ++G) {
    unsigned short* cur = (G & 1) ? Bbuf1 : Bbuf0;
    unsigned short* nxt = (G & 1) ? Bbuf0 : Bbuf1;
    STAGEG(G + 1, nxt)
    const int t0 = 4 * G;
    TILE_MFMA_L(cur + 0 * 3072, 0) TILE_SEL(t0 - 1, 1)
    TILE_MFMA_L(cur + 1 * 3072, 1) TILE_SEL(t0, 0)
    TILE_MFMA_L(cur + 2 * 3072, 0) TILE_SEL(t0 + 1, 1)
    TILE_MFMA_L(cur + 3 * 3072, 1) TILE_SEL(t0 + 2, 0)
    __syncthreads();
  }

  // ---- epilogue: group 63 (tiles 252..255 in Bbuf1), no staging ----
  TILE_MFMA_L(Bbuf1 + 0 * 3072, 0) TILE_SEL(251, 1)
  TILE_MFMA_L(Bbuf1 + 1 * 3072, 1) TILE_SEL(252, 0)
  TILE_MFMA_L(Bbuf1 + 2 * 3072, 0) TILE_SEL(253, 1)
  TILE_MFMA_L(Bbuf1 + 3 * 3072, 1) TILE_SEL(254, 0)
  TILE_SEL(255, 1)

  // final drain
  for (int _k = 0; _k < cnt; ++_k) {
    const float2 e = myring[_k];
    if (e.x < A_kmax) { TS_INS(A_, e.x, __float_as_int(e.y)) }
  }

  const size_t base = ((size_t)(b * NCH + g) * KNN) * NN + isel;
#define TS_ST(P,k) cd[base + (size_t)(k) * NN] = P##m##k; \
                   ci[base + (size_t)(k) * NN] = P##p##k;
  REP20(TS_ST, A_)
#undef TS_ST
}

// ---------------------------------------------------------------------------
// Kernel 3: merge NCH=4 unsorted 20-lists (lex (d, j) compare — exact jax).
// ---------------------------------------------------------------------------
#define TK_LIST(OP) OP(0) OP(1) OP(2) OP(3) OP(4) OP(5) OP(6) OP(7) OP(8) \
    OP(9) OP(10) OP(11) OP(12) OP(13) OP(14) OP(15) OP(16) OP(17) OP(18) OP(19)
#define TK_DECL(k) float td##k = 1e30f; int ti##k = -1;
#define TK_SW(a, b)                                                        \
  {                                                                        \
    const bool _s = (td##b < td##a) ||                                     \
                    ((td##b == td##a) && (ti##b < ti##a));                 \
    const float _fa = _s ? td##b : td##a;                                  \
    const float _fb = _s ? td##a : td##b;                                  \
    const int _ia = _s ? ti##b : ti##a;                                    \
    const int _ib = _s ? ti##a : ti##b;                                    \
    td##a = _fa; td##b = _fb; ti##a = _ia; ti##b = _ib;                    \
  }
#define TK_BUBBLE                                                          \
  TK_SW(18, 19) TK_SW(17, 18) TK_SW(16, 17) TK_SW(15, 16) TK_SW(14, 15)    \
  TK_SW(13, 14) TK_SW(12, 13) TK_SW(11, 12) TK_SW(10, 11) TK_SW(9, 10)     \
  TK_SW(8, 9) TK_SW(7, 8) TK_SW(6, 7) TK_SW(5, 6) TK_SW(4, 5)              \
  TK_SW(3, 4) TK_SW(2, 3) TK_SW(1, 2) TK_SW(0, 1)

__global__ __launch_bounds__(128, 4) void merge_kernel(
    const float* __restrict__ cd, const int* __restrict__ ci,
    int* __restrict__ idxf) {
  const int b = blockIdx.y;
  const int n = blockIdx.x * 128 + threadIdx.x;

  TK_LIST(TK_DECL)

  for (int ch = 0; ch < NCH; ++ch) {
    const size_t base = ((size_t)(b * NCH + ch) * KNN) * NN + n;
    for (int s = 0; s < KNN; ++s) {
      const float d = cd[base + (size_t)s * NN];
      const int j = ci[base + (size_t)s * NN];
      if ((d < td19) || ((d == td19) && (j < ti19))) {
        td19 = d;
        ti19 = j;
        TK_BUBBLE
      }
    }
  }

#define TK_STI(k) idxf[((size_t)b * KNN + (k)) * NN + n] = ti##k;
  TK_LIST(TK_STI)
#undef TK_STI
}

// ---------------------------------------------------------------------------
// Kernel 4: gather + max + leaky + transposed store (R22 version).
// ---------------------------------------------------------------------------
__global__ __launch_bounds__(256) void gather_kernel(
    const unsigned short* __restrict__ Ab16, const float* __restrict__ Q,
    const int* __restrict__ idxf, float* __restrict__ out) {
  __shared__ int jidx[KNN][32];
  __shared__ float ob[32][OO + 2];

  const int b = blockIdx.y;
  const int n0 = blockIdx.x * 32;
  const int t = threadIdx.x;
  const int p = t & 63;
  const int h = t >> 6;

  for (int e = t; e < KNN * 32; e += 256) {
    const int k = e >> 5, ii = e & 31;
    jidx[k][ii] = idxf[((size_t)b * KNN + k) * NN + n0 + ii];
  }
  __syncthreads();

  const unsigned short* Ab = Ab16 + (size_t)b * NN * OO;
  const float* Qb = Q + (size_t)b * NN * OO;

  for (int ii = h * 8; ii < h * 8 + 8; ++ii) {
    float m0 = -1e30f, m1 = -1e30f;
#pragma unroll
    for (int k = 0; k < KNN; ++k) {
      const unsigned v =
          *(const unsigned*)(Ab + (size_t)jidx[k][ii] * OO + 2 * p);
      m0 = fmaxf(m0, __uint_as_float(v << 16));
      m1 = fmaxf(m1, __uint_as_float(v & 0xFFFF0000u));
    }
    const float2 qv = *(const float2*)(Qb + (size_t)(n0 + ii) * OO + 2 * p);
    const float h0 = m0 + qv.x;
    const float h1 = m1 + qv.y;
    ob[ii][2 * p] = (h0 >= 0.f) ? h0 : 0.2f * h0;
    ob[ii][2 * p + 1] = (h1 >= 0.f) ? h1 : 0.2f * h1;
  }
  __syncthreads();

  float* ou = out + (size_t)b * OO * NN;
  for (int e = t; e < 32 * OO; e += 256) {
    const int ii = e & 31, oo = e >> 5;
    ou[(size_t)oo * NN + n0 + ii] = ob[ii][oo];
  }
}

// ---------------------------------------------------------------------------
extern "C" void kernel_launch(void* const* d_in, const int* in_sizes, int n_in,
                              void* d_out, int out_size, void* d_ws,
                              size_t ws_size, hipStream_t stream) {
  (void)in_sizes;
  (void)n_in;
  (void)out_size;
  (void)ws_size;
  const float* x = (const float*)d_in[0];
  const float* W = (const float*)d_in[1];
  const float* bias = (const float*)d_in[2];
  float* out = (float*)d_out;

  char* ws = (char*)d_ws;
  size_t off = 0;
  unsigned short* Ab16 = (unsigned short*)(ws + off);
  off += (size_t)BB * NN * OO * 2;              // 8 MB
  float* Q = (float*)(ws + off);
  off += (size_t)BB * NN * OO * 4;              // 16 MB
  float* xsq = (float*)(ws + off);
  off += (size_t)BB * NN * 4;                   // 128 KB
  unsigned short* xsp = (unsigned short*)(ws + off);
  off += (size_t)BB * NN * SPLITW * 2;          // 12.6 MB
  float* cd = (float*)(ws + off);
  off += (size_t)BB * NCH * KNN * NN * 4;       // 10.5 MB
  int* ci = (int*)(ws + off);
  off += (size_t)BB * NCH * KNN * NN * 4;       // 10.5 MB
  int* idxf = (int*)(ws + off);
  off += (size_t)BB * KNN * NN * 4;             // 2.6 MB
  unsigned short* Wsp = (unsigned short*)(ws + off);
  off += (size_t)OO * WSPL * 2;                 // 96 KB

  wsplit_kernel<<<dim3(OO), 128, 0, stream>>>(W, Wsp);
  xprep_kernel<<<dim3(NN / 128, BB), 128, 0, stream>>>(x, xsq, xsp);
  knn_kernel<<<dim3(NN / 64, BB), 256, 0, stream>>>(xsp, xsq, cd, ci);
  aq_kernel<<<dim3(NN / 64, BB), 256, 0, stream>>>(xsp, Wsp, bias, Ab16, Q);
  merge_kernel<<<dim3(NN / 128, BB), 128, 0, stream>>>(cd, ci, idxf);
  gather_kernel<<<dim3(NN / 32, BB), 256, 0, stream>>>(Ab16, Q, idxf, out);
}